// Round 1
// baseline (12926.494 us; speedup 1.0000x reference)
//
#include <hip/hip_runtime.h>
#include <cmath>

#define HID   512
#define VOCAB 100
#define G3    1536          // 3*HID
#define GEXT  1664          // G3 + 100 logits + pad
#define TMAX  201
#define ROWS  8
#define BLOCK 640
#define NWG   256

// ---- workspace layout (float offsets) ----
#define SZ_GTI   (HID * GEXT)          // 851968: interleaved [kc][j][kk4]
#define OFF_GTI  0
#define SZ_EIH   (VOCAB * G3)          // 153600: E_ih = embed @ W_ih^T + b_ih
#define OFF_EIH  (OFF_GTI + SZ_GTI)
#define SZ_WIHT  (HID * G3)            // 786432: W_ih transposed [k][j]
#define OFF_WIHT (OFF_EIH + SZ_EIH)
#define SZ_BEXT  GEXT                  // 1664: [b_hh | b_proj | 0-pad]
#define OFF_BEXT (OFF_WIHT + SZ_WIHT)
// total = 1,793,664 floats = ~7.2 MB of d_ws

// Build GTI (k4-interleaved extended weight matrix), W_ihT, bias_ext.
// GTI float index = (kc*GEXT + j)*4 + kk, where k = kc*4+kk.
// Columns j: [0,1536) = W_hh rows (r,z,n gates); [1536,1636) = W_proj rows; pad=0.
__global__ void prep_kernel(const float* __restrict__ W_ih,
                            const float* __restrict__ W_hh,
                            const float* __restrict__ b_hh,
                            const float* __restrict__ W_proj,
                            const float* __restrict__ b_proj,
                            float* __restrict__ ws)
{
  int idx = blockIdx.x * blockDim.x + threadIdx.x;
  const int total = SZ_GTI + SZ_WIHT + SZ_BEXT;
  if (idx >= total) return;
  if (idx < SZ_GTI) {
    int kc  = idx / (GEXT * 4);
    int rem = idx - kc * (GEXT * 4);
    int j   = rem >> 2;
    int kk  = rem & 3;
    int k   = kc * 4 + kk;
    float val = 0.f;
    if (j < G3)              val = W_hh[j * HID + k];
    else if (j < G3 + VOCAB) val = W_proj[(j - G3) * HID + k];
    ws[OFF_GTI + idx] = val;
  } else if (idx < SZ_GTI + SZ_WIHT) {
    int e = idx - SZ_GTI;
    int k = e / G3;
    int j = e - k * G3;
    ws[OFF_WIHT + e] = W_ih[j * HID + k];
  } else {
    int j = idx - SZ_GTI - SZ_WIHT;
    float val = 0.f;
    if (j < G3)              val = b_hh[j];
    else if (j < G3 + VOCAB) val = b_proj[j - G3];
    ws[OFF_BEXT + j] = val;
  }
}

// E_ih[v][j] = b_ih[j] + sum_k embed[v][k] * W_ih[j][k]   (coalesced via W_ihT)
__global__ void eih_kernel(const float* __restrict__ embed,
                           const float* __restrict__ b_ih,
                           float* __restrict__ ws)
{
  int v = blockIdx.x / 6;
  int j = (blockIdx.x % 6) * 256 + threadIdx.x;
  const float* WihT = ws + OFF_WIHT;
  const float* e = embed + v * HID;
  float acc = b_ih[j];
  for (int k = 0; k < HID; ++k)
    acc = fmaf(WihT[k * G3 + j], e[k], acc);
  ws[OFF_EIH + v * G3 + j] = acc;
}

// Persistent per-block GRU decode: 8 batch rows per block, 202 iterations.
// Iteration t: extended GEMV on h(=H_t) gives gh_t (cols 0..1535) and
// logits_{t-1} (cols 1536..1635); argmax -> pred_{t-1}; gate math -> H_{t+1}.
__global__ __launch_bounds__(BLOCK) void decode_kernel(
    const float* __restrict__ feat,
    const int* __restrict__ sos,
    const float* __restrict__ ws,
    float* __restrict__ out)
{
  __shared__ float h_lds[ROWS][HID];
  __shared__ float logits_lds[ROWS][132];   // stride 132 breaks argmax bank aliasing
  __shared__ int   pred_lds[ROWS];

  const float* __restrict__ GTI  = ws + OFF_GTI;
  const float* __restrict__ EIH  = ws + OFF_EIH;
  const float* __restrict__ bext = ws + OFF_BEXT;

  const int tid = threadIdx.x;
  const int b0  = blockIdx.x * ROWS;

  for (int i = tid; i < ROWS * HID; i += BLOCK) {
    int r = i >> 9, k = i & (HID - 1);
    h_lds[r][k] = feat[(b0 + r) * HID + k];
  }
  if (tid < ROWS) pred_lds[tid] = sos[0];
  __syncthreads();

  const bool is_gate = (tid < HID);   // threads [0,512): own unit u = tid (r,z,n triplet)
  const int  u = tid;
  const int  v = tid - HID;           // threads [512,640): logit column v in [0,128)

  float bias0 = 0.f, bias1 = 0.f, bias2 = 0.f;
  if (is_gate) { bias0 = bext[u]; bias1 = bext[HID + u]; bias2 = bext[2 * HID + u]; }
  else         { bias0 = bext[G3 + v]; }

  float accr[ROWS], accz[ROWS], accn[ROWS];

  for (int t = 0; t <= TMAX; ++t) {
    // ---------- phase A: extended GEMV over k ----------
    if (is_gate) {
      #pragma unroll
      for (int r = 0; r < ROWS; ++r) { accr[r] = bias0; accz[r] = bias1; accn[r] = bias2; }
      if (t < TMAX) {  // last iteration needs only logits
        const float4* pr = (const float4*)GTI + u;
        const float4* pz = (const float4*)GTI + HID + u;
        const float4* pn = (const float4*)GTI + 2 * HID + u;
        for (int kc = 0; kc < HID / 4; ++kc) {
          float4 wr = pr[kc * GEXT];
          float4 wz = pz[kc * GEXT];
          float4 wn = pn[kc * GEXT];
          #pragma unroll
          for (int r = 0; r < ROWS; ++r) {
            float4 hv = *(const float4*)&h_lds[r][kc * 4];   // LDS broadcast
            accr[r] = fmaf(wr.x, hv.x, accr[r]); accr[r] = fmaf(wr.y, hv.y, accr[r]);
            accr[r] = fmaf(wr.z, hv.z, accr[r]); accr[r] = fmaf(wr.w, hv.w, accr[r]);
            accz[r] = fmaf(wz.x, hv.x, accz[r]); accz[r] = fmaf(wz.y, hv.y, accz[r]);
            accz[r] = fmaf(wz.z, hv.z, accz[r]); accz[r] = fmaf(wz.w, hv.w, accz[r]);
            accn[r] = fmaf(wn.x, hv.x, accn[r]); accn[r] = fmaf(wn.y, hv.y, accn[r]);
            accn[r] = fmaf(wn.z, hv.z, accn[r]); accn[r] = fmaf(wn.w, hv.w, accn[r]);
          }
        }
      }
    } else {
      #pragma unroll
      for (int r = 0; r < ROWS; ++r) accr[r] = bias0;
      const float4* pv = (const float4*)GTI + G3 + v;
      for (int kc = 0; kc < HID / 4; ++kc) {
        float4 wv = pv[kc * GEXT];
        #pragma unroll
        for (int r = 0; r < ROWS; ++r) {
          float4 hv = *(const float4*)&h_lds[r][kc * 4];
          accr[r] = fmaf(wv.x, hv.x, accr[r]); accr[r] = fmaf(wv.y, hv.y, accr[r]);
          accr[r] = fmaf(wv.z, hv.z, accr[r]); accr[r] = fmaf(wv.w, hv.w, accr[r]);
        }
      }
      #pragma unroll
      for (int r = 0; r < ROWS; ++r) logits_lds[r][v] = accr[r];
      if (t >= 1 && v < VOCAB) {   // logits_{t-1} -> out[b][v][t-1]
        #pragma unroll
        for (int r = 0; r < ROWS; ++r)
          __builtin_nontemporal_store(
              accr[r], &out[((size_t)(b0 + r) * VOCAB + v) * TMAX + (t - 1)]);
      }
    }
    __syncthreads();

    // ---------- argmax (first-max, matches jnp.argmax) ----------
    if (t >= 1 && t < TMAX && tid < ROWS) {
      float best = logits_lds[tid][0];
      int bi = 0;
      for (int x = 1; x < VOCAB; ++x) {
        float val = logits_lds[tid][x];
        if (val > best) { best = val; bi = x; }
      }
      pred_lds[tid] = bi;
    }
    __syncthreads();

    // ---------- gate nonlinearity + h update (no gh LDS round-trip) ----------
    if (is_gate && t < TMAX) {
      #pragma unroll
      for (int r = 0; r < ROWS; ++r) {
        const float* eb = EIH + (size_t)pred_lds[r] * G3;
        float gir = eb[u], giz = eb[HID + u], gin = eb[2 * HID + u];
        float rg = 1.f / (1.f + expf(-(gir + accr[r])));
        float zg = 1.f / (1.f + expf(-(giz + accz[r])));
        float ng = tanhf(gin + rg * accn[r]);
        h_lds[r][u] = (1.f - zg) * ng + zg * h_lds[r][u];
      }
    }
    __syncthreads();
  }
}

extern "C" void kernel_launch(void* const* d_in, const int* in_sizes, int n_in,
                              void* d_out, int out_size, void* d_ws, size_t ws_size,
                              hipStream_t stream)
{
  const float* feat   = (const float*)d_in[0];
  const float* W_ih   = (const float*)d_in[1];
  const float* W_hh   = (const float*)d_in[2];
  const float* b_ih   = (const float*)d_in[3];
  const float* b_hh   = (const float*)d_in[4];
  const float* W_proj = (const float*)d_in[5];
  const float* b_proj = (const float*)d_in[6];
  const float* embed  = (const float*)d_in[7];
  const int*   sos    = (const int*)d_in[8];
  float* ws  = (float*)d_ws;
  float* out = (float*)d_out;

  const int total = SZ_GTI + SZ_WIHT + SZ_BEXT;
  prep_kernel<<<(total + 255) / 256, 256, 0, stream>>>(W_ih, W_hh, b_hh, W_proj, b_proj, ws);
  eih_kernel<<<600, 256, 0, stream>>>(embed, b_ih, ws);
  decode_kernel<<<NWG, BLOCK, 0, stream>>>(feat, sos, ws, out);
}